// Round 4
// baseline (489.864 us; speedup 1.0000x reference)
//
#include <hip/hip_runtime.h>
#include <stdint.h>

// Voxelization, scales {2,4,8,1}.
//  - pow2 dims => scale-s index == scale-1 index >> log2(s), bit-exact in f32
//  - k_mark: scale-1 bitmap only, fire-and-forget atomicOr
//  - coarse bitmaps by coalesced OR-downsample (bit compression)
//  - rank(key) = blockBase[w>>12] + relM[w>>10] + relB16[w>>2] + in-line popc
//    (random stream touches only bitmap(16.8MB) + relB(2.4MB, L2-resident))
// Dispatches: memset, mark, down2, down48, scan1, scan2, writeuniq.

#define CHUNK 4096
#define NB    1174
#define TOTALW 4808704
#define NGROUP (TOTALW / 4)     // 1202176 (4-word groups)
#define NSUB   (TOTALW / 1024)  // 4696   (1024-word subblocks)
// region word offsets, scale order {2,4,8,1}; chunk boundaries 129,146,149
#define R_S2 0
#define R_S4 528384
#define R_S8 598016
#define R_S1 610304

__device__ __forceinline__ uint32_t cmp2(uint32_t w) {
  // result bit i = w[2i] | w[2i+1]  (32->16; also 16->8 with zero upper)
  w = (w | (w >> 1)) & 0x55555555u;
  w = (w | (w >> 1)) & 0x33333333u;
  w = (w | (w >> 2)) & 0x0F0F0F0Fu;
  w = (w | (w >> 4)) & 0x00FF00FFu;
  w = (w | (w >> 8)) & 0x0000FFFFu;
  return w;
}

__global__ __launch_bounds__(256) void k_mark(
    const float* __restrict__ pts, const int* __restrict__ bidx, int n,
    uint32_t* __restrict__ keys, uint32_t* __restrict__ bitmap) {
  int j = blockIdx.x * 256 + threadIdx.x;
  if (j >= n) return;
  float px = pts[3 * j + 0];
  float py = pts[3 * j + 1];
  float pz = pts[3 * j + 2];
  int b = bidx[j];
  // exact reference arithmetic at scale 1 (f32 mul, add, div, trunc)
  int x1 = (int)((512.0f * (px + 51.2f)) / 102.4f);
  int y1 = (int)((512.0f * (py + 51.2f)) / 102.4f);
  int z1 = (int)((64.0f * (pz + 4.0f)) / 6.4f);
  keys[j] = ((uint32_t)b << 27) | ((uint32_t)x1 << 17) | ((uint32_t)y1 << 7) | (uint32_t)z1;
  uint32_t key = (uint32_t)(((b * 512 + x1) * 512 + y1) * 64 + z1);
  atomicOr(&bitmap[R_S1 + (key >> 5)], 1u << (key & 31u));  // fire & forget
}

// scale-1 -> scale-2: out word per (b,X,Y), 32 Z-bits
__global__ __launch_bounds__(256) void k_down2(
    const uint32_t* __restrict__ bm, uint32_t* __restrict__ out) {
  int o = blockIdx.x * 256 + threadIdx.x;  // (b*256+X)*256+Y, 524288 total
  int Y = o & 255, X = (o >> 8) & 255, b = o >> 16;
  const uint4* p = (const uint4*)(bm + R_S1 + (size_t)(((b * 512 + 2 * X) * 512) + 2 * Y) * 2);
  uint4 A = p[0];    // x=2X
  uint4 B = p[256];  // x=2X+1
  uint32_t lo = A.x | A.z | B.x | B.z;
  uint32_t hi = A.y | A.w | B.y | B.w;
  out[R_S2 + o] = cmp2(lo) | (cmp2(hi) << 16);
}

// scale-4 and scale-8, both derived from scale-2 (independent)
__global__ __launch_bounds__(256) void k_down48(
    const uint32_t* __restrict__ bm, uint32_t* __restrict__ out) {
  int o = blockIdx.x * 256 + threadIdx.x;
  if (o < 65536) {
    // scale-2 -> scale-4: word per (b,X,k): Y=2k (lo16), Y=2k+1 (hi16)
    int k = o & 63, X = (o >> 6) & 127, b = o >> 13;
    const uint4* p = (const uint4*)(bm + R_S2 + (size_t)(((b * 256 + 2 * X) * 256) + 4 * k));
    uint4 A = p[0];   // x2=2X
    uint4 B = p[64];  // x2=2X+1
    uint32_t lo = A.x | A.y | B.x | B.y;
    uint32_t hi = A.z | A.w | B.z | B.w;
    out[R_S4 + o] = cmp2(lo) | (cmp2(hi) << 16);
  } else {
    // scale-2 -> scale-8: word per (b,X8,k): Y8=4k+j at byte j, 8 Z-bits
    int o8 = o - 65536;  // 8192 total
    int k = o8 & 15, X8 = (o8 >> 4) & 63, b = o8 >> 10;
    uint32_t res = 0;
#pragma unroll
    for (int j = 0; j < 4; j++) {
      uint32_t acc = 0;
      int y2 = 16 * k + 4 * j;
#pragma unroll
      for (int xr = 0; xr < 4; xr++) {
        const uint4* p = (const uint4*)(bm + R_S2 + (size_t)((b * 256 + 4 * X8 + xr) * 256 + y2));
        uint4 v = *p;
        acc |= v.x | v.y | v.z | v.w;
      }
      res |= cmp2(cmp2(acc)) << (8 * j);
    }
    out[R_S8 + o8] = res;
  }
}

// One pass over the bitmap: per-chunk total + per-subblock(1024w) and
// per-group(4w) relative prefixes.
__global__ __launch_bounds__(256) void k_scan1(
    const uint32_t* __restrict__ bitmap, uint32_t* __restrict__ chunkSums,
    uint32_t* __restrict__ relM, uint16_t* __restrict__ relB) {
  __shared__ uint32_t sh[256];
  __shared__ uint32_t shE[256];
  int t = threadIdx.x;
  size_t w0 = (size_t)blockIdx.x * CHUNK + t * 16;
  const uint4* bp = (const uint4*)(bitmap + w0);
  uint4 v0 = bp[0], v1 = bp[1], v2 = bp[2], v3 = bp[3];
  uint32_t g0 = __popc(v0.x) + __popc(v0.y) + __popc(v0.z) + __popc(v0.w);
  uint32_t g1 = __popc(v1.x) + __popc(v1.y) + __popc(v1.z) + __popc(v1.w);
  uint32_t g2 = __popc(v2.x) + __popc(v2.y) + __popc(v2.z) + __popc(v2.w);
  uint32_t g3 = __popc(v3.x) + __popc(v3.y) + __popc(v3.z) + __popc(v3.w);
  uint32_t s = g0 + g1 + g2 + g3;
  sh[t] = s;
  __syncthreads();
  for (int off = 1; off < 256; off <<= 1) {
    uint32_t add = (t >= off) ? sh[t - off] : 0u;
    __syncthreads();
    sh[t] += add;
    __syncthreads();
  }
  shE[t] = sh[t] - s;  // exclusive prefix within chunk
  __syncthreads();
  uint32_t excl = shE[t];
  uint32_t esb = shE[t & 192];  // prefix at this thread's 1024-word subblock start
  uint32_t r0 = excl - esb;
  ((ushort4*)relB)[blockIdx.x * 256 + t] = make_ushort4(
      (unsigned short)r0, (unsigned short)(r0 + g0),
      (unsigned short)(r0 + g0 + g1), (unsigned short)(r0 + g0 + g1 + g2));
  if ((t & 63) == 0) relM[blockIdx.x * 4 + (t >> 6)] = excl;
  if (t == 255) chunkSums[blockIdx.x] = sh[255];
}

// Single block: exclusive-scan chunkSums -> blockBase (in place); devOff/devRank.
__global__ __launch_bounds__(256) void k_scan2(
    uint32_t* chunkSums, long long* devOff, uint32_t* devRank, long long fiveN) {
  __shared__ uint32_t sh[256];
  __shared__ uint32_t shB[3];
  int t = threadIdx.x;
  uint32_t v[8];
  uint32_t s = 0;
#pragma unroll
  for (int k = 0; k < 8; k++) {
    int idx = t * 8 + k;
    uint32_t x = (idx < NB) ? chunkSums[idx] : 0u;
    v[k] = x;
    s += x;
  }
  sh[t] = s;
  __syncthreads();
  for (int off = 1; off < 256; off <<= 1) {
    uint32_t add = (t >= off) ? sh[t - off] : 0u;
    __syncthreads();
    sh[t] += add;
    __syncthreads();
  }
  uint32_t run = sh[t] - s;
#pragma unroll
  for (int k = 0; k < 8; k++) {
    int idx = t * 8 + k;
    if (idx < NB) chunkSums[idx] = run;
    if (idx == 129) shB[0] = run;
    if (idx == 146) shB[1] = run;
    if (idx == 149) shB[2] = run;
    run += v[k];
  }
  __syncthreads();
  if (t == 0) {
    uint32_t tot = sh[255];
    uint32_t T0 = shB[0];
    uint32_t T1 = shB[1] - shB[0];
    uint32_t T2 = shB[2] - shB[1];
    uint32_t T3 = tot - shB[2];
    devOff[0] = 0;
    devOff[1] = devOff[0] + fiveN + 4LL * T0;
    devOff[2] = devOff[1] + fiveN + 4LL * T1;
    devOff[3] = devOff[2] + fiveN + 4LL * T2;
    devOff[4] = devOff[3] + fiveN + 4LL * T3;
    devRank[0] = 0;       // scale-2 region base rank
    devRank[1] = shB[0];  // scale-4
    devRank[2] = shB[1];  // scale-8
    devRank[3] = shB[2];  // scale-1
  }
}

__device__ __forceinline__ uint32_t rank_lookup(
    const uint32_t* __restrict__ bm, const uint32_t* __restrict__ blockBase,
    const uint32_t* __restrict__ relM, const uint16_t* __restrict__ relB,
    uint32_t w, uint32_t bit) {
  uint32_t g = w >> 2;
  uint4 wv = *(const uint4*)(bm + ((size_t)g << 2));
  uint32_t r = blockBase[w >> 12] + relM[w >> 10] + (uint32_t)relB[g];
  uint32_t k = w & 3u;
  if (k > 0) r += __popc(wv.x);
  if (k > 1) r += __popc(wv.y);
  if (k > 2) r += __popc(wv.z);
  uint32_t word = (k == 0) ? wv.x : (k == 1) ? wv.y : (k == 2) ? wv.z : wv.w;
  return r + __popc(word & ((1u << bit) - 1u));
}

template <int LZ, int LYZ, int LB, int MZ, int MY, int MX, int RG, int SI>
__device__ __forceinline__ void uniq_group4(
    uint32_t w0, uint4 wv, uint32_t pos, uint32_t rankBase,
    const long long* __restrict__ devOff, int* __restrict__ out, long long fiveN) {
  uint32_t words[4] = {wv.x, wv.y, wv.z, wv.w};
  pos -= rankBase;
  long long base = devOff[SI] + fiveN;
  uint32_t local0 = w0 - (uint32_t)RG;
#pragma unroll
  for (int k = 0; k < 4; k++) {
    uint32_t wd = words[k];
    uint32_t local = local0 + (uint32_t)k;
    while (wd) {
      int bit = __ffs(wd) - 1;
      wd &= wd - 1u;
      uint32_t key = (local << 5) + (uint32_t)bit;
      int z = (int)(key & (uint32_t)MZ);
      int y = (int)((key >> LZ) & (uint32_t)MY);
      int x = (int)((key >> LYZ) & (uint32_t)MX);
      int bb = (int)(key >> LB);
      *(int4*)(out + base + 4LL * pos) = make_int4(bb, z, y, x);
      pos++;
    }
  }
}

__global__ __launch_bounds__(256) void k_writeuniq(
    const uint32_t* __restrict__ keys, int n, int gridN,
    const uint32_t* __restrict__ bitmap, const uint32_t* __restrict__ blockBase,
    const uint32_t* __restrict__ relM, const uint16_t* __restrict__ relB,
    const uint32_t* __restrict__ devRank, const long long* __restrict__ devOff,
    int* __restrict__ out, long long fourN, long long fiveN) {
  int blk = blockIdx.x;
  if (blk < gridN) {
    // per-point full_coors + inverse index, all 4 scales
    int j = blk * 256 + threadIdx.x;
    if (j >= n) return;
    uint32_t p = keys[j];
    int b = (int)(p >> 27);
    int x1 = (int)((p >> 17) & 1023u);
    int y1 = (int)((p >> 7) & 1023u);
    int z1 = (int)(p & 127u);
    const int SX[4] = {256, 128, 64, 512};
    const int SY[4] = {256, 128, 64, 512};
    const int SZ[4] = {32, 16, 8, 64};
    const int SH[4] = {1, 2, 3, 0};
    const int RG[4] = {R_S2, R_S4, R_S8, R_S1};
#pragma unroll
    for (int i = 0; i < 4; i++) {
      int sh = SH[i];
      int xi = x1 >> sh, yi = y1 >> sh, zi = z1 >> sh;
      uint32_t key = (uint32_t)(((b * SX[i] + xi) * SY[i] + yi) * SZ[i] + zi);
      uint32_t w = (uint32_t)RG[i] + (key >> 5);
      uint32_t rank = rank_lookup(bitmap, blockBase, relM, relB, w, key & 31u);
      long long o = devOff[i];
      *(int4*)(out + o + 4LL * j) = make_int4(b, xi, yi, zi);
      out[o + fourN + j] = (int)(rank - devRank[i]);
    }
  } else {
    // unique coords: one thread per 4-word group
    int g = (blk - gridN) * 256 + threadIdx.x;  // < NGROUP exactly
    uint4 wv = *(const uint4*)(bitmap + ((size_t)g << 2));
    if (!(wv.x | wv.y | wv.z | wv.w)) return;
    uint32_t w0 = (uint32_t)g << 2;
    uint32_t pos = blockBase[w0 >> 12] + relM[w0 >> 10] + (uint32_t)relB[g];
    if (w0 < R_S4) {
      uniq_group4<5, 13, 21, 31, 255, 255, R_S2, 0>(w0, wv, pos, devRank[0], devOff, out, fiveN);
    } else if (w0 < R_S8) {
      uniq_group4<4, 11, 18, 15, 127, 127, R_S4, 1>(w0, wv, pos, devRank[1], devOff, out, fiveN);
    } else if (w0 < R_S1) {
      uniq_group4<3, 9, 15, 7, 63, 63, R_S8, 2>(w0, wv, pos, devRank[2], devOff, out, fiveN);
    } else {
      uniq_group4<6, 15, 24, 63, 511, 511, R_S1, 3>(w0, wv, pos, devRank[3], devOff, out, fiveN);
    }
  }
}

extern "C" void kernel_launch(void* const* d_in, const int* in_sizes, int n_in,
                              void* d_out, int out_size, void* d_ws, size_t ws_size,
                              hipStream_t stream) {
  const float* pts = (const float*)d_in[0];
  const int* bidx = (const int*)d_in[1];
  int n = in_sizes[0] / 3;
  int* out = (int*)d_out;

  char* ws = (char*)d_ws;
  long long* devOff = (long long*)ws;                 // 5 * 8 B
  uint32_t* devRank = (uint32_t*)(ws + 64);           // 4 * 4 B
  uint32_t* chunkSums = (uint32_t*)(ws + 256);        // NB * 4 B (-> blockBase)
  uint32_t* bitmap = (uint32_t*)(ws + 8192);          // TOTALW * 4 B
  uint32_t* relM = (uint32_t*)(ws + 19243008);        // NSUB * 4 B
  uint16_t* relB = (uint16_t*)(ws + 19262464);        // NGROUP * 2 B
  uint32_t* keys = (uint32_t*)(ws + 21666816);        // n * 4 B

  const long long fourN = 4LL * n, fiveN = 5LL * n;
  const int gridN = (n + 255) / 256;

  hipMemsetAsync(bitmap, 0, (size_t)TOTALW * 4, stream);
  hipLaunchKernelGGL(k_mark, dim3(gridN), dim3(256), 0, stream, pts, bidx, n, keys, bitmap);
  hipLaunchKernelGGL(k_down2, dim3(2048), dim3(256), 0, stream, bitmap, bitmap);
  hipLaunchKernelGGL(k_down48, dim3(288), dim3(256), 0, stream, bitmap, bitmap);
  hipLaunchKernelGGL(k_scan1, dim3(NB), dim3(256), 0, stream, bitmap, chunkSums, relM, relB);
  hipLaunchKernelGGL(k_scan2, dim3(1), dim3(256), 0, stream, chunkSums, devOff, devRank, fiveN);
  hipLaunchKernelGGL(k_writeuniq, dim3(gridN + NGROUP / 256), dim3(256), 0, stream,
                     keys, n, gridN, bitmap, chunkSums, relM, relB,
                     devRank, devOff, out, fourN, fiveN);
}

// Round 5
// 460.659 us; speedup vs baseline: 1.0634x; 1.0634x over previous
//
#include <hip/hip_runtime.h>
#include <stdint.h>

// Voxelization, scales {2,4,8,1}.
//  - pow2 dims => scale-s index == scale-1 index >> log2(s), bit-exact in f32
//  - k_key: compute packed keys + partition s1 keys into 512 spatial buckets
//    (LDS multi-split, coalesced flush) -- NO global atomics on the bitmap
//  - k_bucket: per bucket, build 32KB s1 region in LDS (LDS atomicOr) and
//    derive s2/s4/s8 regions in-LDS; all global stores coalesced
//  - rank(key) via popcount-prefix; bitmap+prefix interleaved as uint2 pairs
//    (one 8B load per rank lookup -- R3-proven path)
// Dispatches: memset(bitmap), memset(counters), key, bucket, sumA, scanB, pref,
//             write, uniq.

#define CHUNK 4096
#define NB    1174
#define TOTALW 4808704
// region word offsets, scale order {2,4,8,1}; chunk boundaries 129,146,149
#define R_S2 0
#define R_S4 528384
#define R_S8 598016
#define R_S1 610304
// bucketing: 512 buckets, each covers 2^18 s1 bits = 8192 words = 8 x1-slices
#define NBUCKET 512
#define BCAP 5120
#define ROUND 4096

__device__ __forceinline__ uint32_t cmp2(uint32_t w) {
  // result bit i = w[2i] | w[2i+1]  (32->16; also 16->8 with zero upper)
  w = (w | (w >> 1)) & 0x55555555u;
  w = (w | (w >> 1)) & 0x33333333u;
  w = (w | (w >> 2)) & 0x0F0F0F0Fu;
  w = (w | (w >> 4)) & 0x00FF00FFu;
  w = (w | (w >> 8)) & 0x0000FFFFu;
  return w;
}

// ---- phase 1: keys + bucket partition ----
__global__ __launch_bounds__(256) void k_key(
    const float* __restrict__ pts, const int* __restrict__ bidx, int n,
    uint32_t* __restrict__ keys, uint32_t* __restrict__ bitmap,
    uint32_t* __restrict__ bucketCount, uint32_t* __restrict__ bucketData) {
  __shared__ uint32_t cnt[NBUCKET], inc[NBUCKET], pos[NBUCKET], gpos[NBUCKET];
  __shared__ uint32_t shs[256];
  __shared__ uint32_t scratch[ROUND];
  int t = threadIdx.x;

  for (int r = 0; r < 2; r++) {
    int base = (blockIdx.x * 2 + r) * ROUND;
    cnt[t] = 0; cnt[t + 256] = 0;
    pos[t] = 0; pos[t + 256] = 0;
    __syncthreads();

    uint32_t myKey[16];
    int myBk[16];
#pragma unroll
    for (int k = 0; k < 16; k++) {
      int j = base + k * 256 + t;
      myBk[k] = -1;
      if (j < n) {
        float px = pts[3 * j + 0];
        float py = pts[3 * j + 1];
        float pz = pts[3 * j + 2];
        int b = bidx[j];
        // exact reference arithmetic at scale 1 (f32 mul, add, div, trunc)
        int x1 = (int)((512.0f * (px + 51.2f)) / 102.4f);
        int y1 = (int)((512.0f * (py + 51.2f)) / 102.4f);
        int z1 = (int)((64.0f * (pz + 4.0f)) / 6.4f);
        keys[j] = ((uint32_t)b << 27) | ((uint32_t)x1 << 17) | ((uint32_t)y1 << 7) | (uint32_t)z1;
        uint32_t s1k = (uint32_t)(((b * 512 + x1) * 512 + y1) * 64 + z1);
        if (s1k >= (1u << 27)) {
          // fold-over edge (prob ~0): direct atomics into padding words
          atomicOr(&bitmap[R_S1 + (s1k >> 5)], 1u << (s1k & 31u));
          uint32_t k2 = (uint32_t)(((b * 256 + (x1 >> 1)) * 256 + (y1 >> 1)) * 32 + (z1 >> 1));
          atomicOr(&bitmap[R_S2 + (k2 >> 5)], 1u << (k2 & 31u));
          uint32_t k4 = (uint32_t)(((b * 128 + (x1 >> 2)) * 128 + (y1 >> 2)) * 16 + (z1 >> 2));
          atomicOr(&bitmap[R_S4 + (k4 >> 5)], 1u << (k4 & 31u));
          uint32_t k8 = (uint32_t)(((b * 64 + (x1 >> 3)) * 64 + (y1 >> 3)) * 8 + (z1 >> 3));
          atomicOr(&bitmap[R_S8 + (k8 >> 5)], 1u << (k8 & 31u));
        } else {
          int bk = (int)(s1k >> 18);
          myBk[k] = bk;
          myKey[k] = s1k;
          atomicAdd(&cnt[bk], 1u);
        }
      }
    }
    __syncthreads();

    // global reservation (cnt final)
    uint32_t c0 = cnt[2 * t], c1 = cnt[2 * t + 1];
    gpos[2 * t] = c0 ? atomicAdd(&bucketCount[2 * t], c0) : 0u;
    gpos[2 * t + 1] = c1 ? atomicAdd(&bucketCount[2 * t + 1], c1) : 0u;
    // inclusive scan of cnt -> inc (pairwise + 256-scan)
    uint32_t s = c0 + c1;
    shs[t] = s;
    __syncthreads();
    for (int off = 1; off < 256; off <<= 1) {
      uint32_t add = (t >= off) ? shs[t - off] : 0u;
      __syncthreads();
      shs[t] += add;
      __syncthreads();
    }
    inc[2 * t] = shs[t] - s + c0;
    inc[2 * t + 1] = shs[t];
    __syncthreads();
    uint32_t total = shs[255];

    // scatter into bucket-contiguous LDS scratch
#pragma unroll
    for (int k = 0; k < 16; k++) {
      if (myBk[k] >= 0) {
        int bk = myBk[k];
        uint32_t slot = inc[bk] - cnt[bk] + atomicAdd(&pos[bk], 1u);
        scratch[slot] = myKey[k];
      }
    }
    __syncthreads();

    // flush: consecutive p -> contiguous global per bucket
#pragma unroll
    for (int m = 0; m < 16; m++) {
      uint32_t p = (uint32_t)(m * 256 + t);
      if (p < total) {
        int lo = 0, hi = NBUCKET - 1;
        while (lo < hi) {
          int mid = (lo + hi) >> 1;
          if (inc[mid] > p) hi = mid; else lo = mid + 1;
        }
        uint32_t lidx = p - (inc[lo] - cnt[lo]);
        uint32_t g = gpos[lo] + lidx;
        if (g < BCAP) bucketData[(size_t)lo * BCAP + g] = scratch[p];
      }
    }
    __syncthreads();
  }
}

// ---- phase 2: per-bucket LDS bitmap build + in-LDS downsample ----
__global__ __launch_bounds__(256) void k_bucket(
    const uint32_t* __restrict__ bucketCount, const uint32_t* __restrict__ bucketData,
    uint32_t* __restrict__ bitmap) {
  __shared__ uint32_t s1L[8192];
  __shared__ uint32_t s2L[1024];
  __shared__ uint32_t s4L[128];
  int bk = blockIdx.x, t = threadIdx.x;

  uint4 z4 = make_uint4(0, 0, 0, 0);
  for (int i = t; i < 2048; i += 256) ((uint4*)s1L)[i] = z4;
  __syncthreads();

  uint32_t c = bucketCount[bk];
  if (c > BCAP) c = BCAP;
  const uint32_t* src = bucketData + (size_t)bk * BCAP;
  for (uint32_t i = t; i < c; i += 256) {
    uint32_t key = src[i];
    uint32_t local = key & 0x3FFFFu;  // 2^18 bits per bucket
    atomicOr(&s1L[local >> 5], 1u << (local & 31u));
  }
  __syncthreads();

  // write s1 region (coalesced)
  uint4* g1 = (uint4*)(bitmap + R_S1 + (size_t)bk * 8192);
  for (int i = t; i < 2048; i += 256) g1[i] = ((uint4*)s1L)[i];

  // s2 from s1 (local layout: s1 word = (x1rel*512 + y1)*2 + h, x1rel in [0,8))
  for (int i = t; i < 1024; i += 256) {
    int x2r = i >> 8, Y2 = i & 255;
    int a = (2 * x2r * 512 + 2 * Y2) * 2;
    int b2 = ((2 * x2r + 1) * 512 + 2 * Y2) * 2;
    uint32_t Ax = s1L[a], Ay = s1L[a + 1], Az = s1L[a + 2], Aw = s1L[a + 3];
    uint32_t Bx = s1L[b2], By = s1L[b2 + 1], Bz = s1L[b2 + 2], Bw = s1L[b2 + 3];
    s2L[i] = cmp2(Ax | Az | Bx | Bz) | (cmp2(Ay | Aw | By | Bw) << 16);
  }
  __syncthreads();
  for (int i = t; i < 1024; i += 256) bitmap[R_S2 + (size_t)bk * 1024 + i] = s2L[i];

  // s4 from s2 (s2 local: x2rel*256 + y2, x2rel in [0,4))
  if (t < 128) {
    int x4r = t >> 6, kk = t & 63;
    int a = (2 * x4r) * 256 + 4 * kk;
    int b4 = (2 * x4r + 1) * 256 + 4 * kk;
    uint32_t A0 = s2L[a], A1 = s2L[a + 1], A2 = s2L[a + 2], A3 = s2L[a + 3];
    uint32_t B0 = s2L[b4], B1 = s2L[b4 + 1], B2 = s2L[b4 + 2], B3 = s2L[b4 + 3];
    s4L[t] = cmp2(A0 | A1 | B0 | B1) | (cmp2(A2 | A3 | B2 | B3) << 16);
  }
  __syncthreads();
  if (t < 128) bitmap[R_S4 + (size_t)bk * 128 + t] = s4L[t];

  // s8 from s4 (s4 local: x4rel*64 + kk, x4rel in {0,1})
  if (t < 16) {
    uint32_t res = 0;
#pragma unroll
    for (int j = 0; j < 4; j++) {
      uint32_t u = s4L[4 * t + j] | s4L[64 + 4 * t + j];
      u = (u | (u >> 16)) & 0xFFFFu;
      res |= cmp2(u) << (8 * j);
    }
    bitmap[R_S8 + (size_t)bk * 16 + t] = res;
  }
}

// ---- scan / rank infrastructure (R3-verbatim) ----
__global__ __launch_bounds__(256) void k_sumA(
    const uint32_t* __restrict__ bitmap, uint32_t* __restrict__ blockSums) {
  __shared__ uint32_t sh[256];
  int t = threadIdx.x;
  const uint4* bp = (const uint4*)(bitmap + (size_t)blockIdx.x * CHUNK + t * 16);
  uint32_t s = 0;
#pragma unroll
  for (int k = 0; k < 4; k++) {
    uint4 v = bp[k];
    s += __popc(v.x) + __popc(v.y) + __popc(v.z) + __popc(v.w);
  }
  sh[t] = s;
  __syncthreads();
  for (int off = 128; off > 0; off >>= 1) {
    if (t < off) sh[t] += sh[t + off];
    __syncthreads();
  }
  if (t == 0) blockSums[blockIdx.x] = sh[0];
}

__global__ __launch_bounds__(256) void k_scanB(
    uint32_t* blockSums, long long* devOff, uint32_t* devRank, long long fiveN) {
  __shared__ uint32_t sh[256];
  __shared__ uint32_t shB[3];
  int t = threadIdx.x;
  uint32_t v[8];
  uint32_t s = 0;
#pragma unroll
  for (int k = 0; k < 8; k++) {
    int idx = t * 8 + k;
    uint32_t x = (idx < NB) ? blockSums[idx] : 0u;
    v[k] = x;
    s += x;
  }
  sh[t] = s;
  __syncthreads();
  for (int off = 1; off < 256; off <<= 1) {
    uint32_t add = (t >= off) ? sh[t - off] : 0u;
    __syncthreads();
    sh[t] += add;
    __syncthreads();
  }
  uint32_t run = sh[t] - s;
#pragma unroll
  for (int k = 0; k < 8; k++) {
    int idx = t * 8 + k;
    if (idx < NB) blockSums[idx] = run;
    if (idx == 129) shB[0] = run;
    if (idx == 146) shB[1] = run;
    if (idx == 149) shB[2] = run;
    run += v[k];
  }
  __syncthreads();
  if (t == 0) {
    uint32_t tot = sh[255];
    uint32_t T0 = shB[0];
    uint32_t T1 = shB[1] - shB[0];
    uint32_t T2 = shB[2] - shB[1];
    uint32_t T3 = tot - shB[2];
    devOff[0] = 0;
    devOff[1] = devOff[0] + fiveN + 4LL * T0;
    devOff[2] = devOff[1] + fiveN + 4LL * T1;
    devOff[3] = devOff[2] + fiveN + 4LL * T2;
    devOff[4] = devOff[3] + fiveN + 4LL * T3;
    devRank[0] = 0;
    devRank[1] = shB[0];
    devRank[2] = shB[1];
    devRank[3] = shB[2];
  }
}

__global__ __launch_bounds__(256) void k_pref(
    const uint32_t* __restrict__ bitmap, const uint32_t* __restrict__ blockSums,
    uint2* __restrict__ pairs) {
  __shared__ uint32_t sh[256];
  int t = threadIdx.x;
  size_t w0 = (size_t)blockIdx.x * CHUNK + t * 16;
  const uint4* bp = (const uint4*)(bitmap + w0);
  uint4 words[4];
  uint32_t s = 0;
#pragma unroll
  for (int k = 0; k < 4; k++) {
    uint4 v = bp[k];
    words[k] = v;
    s += __popc(v.x) + __popc(v.y) + __popc(v.z) + __popc(v.w);
  }
  sh[t] = s;
  __syncthreads();
  for (int off = 1; off < 256; off <<= 1) {
    uint32_t add = (t >= off) ? sh[t - off] : 0u;
    __syncthreads();
    sh[t] += add;
    __syncthreads();
  }
  uint32_t run = blockSums[blockIdx.x] + (sh[t] - s);
  uint4* pp = (uint4*)(pairs + w0);
#pragma unroll
  for (int k = 0; k < 4; k++) {
    uint4 o1, o2;
    o1.x = words[k].x; o1.y = run; run += __popc(words[k].x);
    o1.z = words[k].y; o1.w = run; run += __popc(words[k].y);
    o2.x = words[k].z; o2.y = run; run += __popc(words[k].z);
    o2.z = words[k].w; o2.w = run; run += __popc(words[k].w);
    pp[2 * k] = o1;
    pp[2 * k + 1] = o2;
  }
}

__global__ __launch_bounds__(256) void k_write(
    const uint32_t* __restrict__ keys, int n, const uint2* __restrict__ pairs,
    const uint32_t* __restrict__ devRank, const long long* __restrict__ devOff,
    int* __restrict__ out, long long fourN) {
  int j = blockIdx.x * 256 + threadIdx.x;
  if (j >= n) return;
  uint32_t p = keys[j];
  int b = (int)(p >> 27);
  int x1 = (int)((p >> 17) & 1023u);
  int y1 = (int)((p >> 7) & 1023u);
  int z1 = (int)(p & 127u);
  const int SX[4] = {256, 128, 64, 512};
  const int SY[4] = {256, 128, 64, 512};
  const int SZ[4] = {32, 16, 8, 64};
  const int SH[4] = {1, 2, 3, 0};
  const int RG[4] = {R_S2, R_S4, R_S8, R_S1};
#pragma unroll
  for (int i = 0; i < 4; i++) {
    int sh = SH[i];
    int xi = x1 >> sh, yi = y1 >> sh, zi = z1 >> sh;
    uint32_t key = (uint32_t)(((b * SX[i] + xi) * SY[i] + yi) * SZ[i] + zi);
    uint2 pr = pairs[RG[i] + (key >> 5)];
    long long o = devOff[i];
    *(int4*)(out + o + 4LL * j) = make_int4(b, xi, yi, zi);
    uint32_t inv = pr.y + __popc(pr.x & ((1u << (key & 31u)) - 1u)) - devRank[i];
    out[o + fourN + j] = (int)inv;
  }
}

template <int LZ, int LYZ, int LB, int MZ, int MY, int MX, int RG, int SCALE_IDX>
__device__ __forceinline__ void uniq_region(
    uint32_t w, uint32_t wd, uint32_t pf, uint32_t rankBase,
    const long long* __restrict__ devOff, int* __restrict__ out, long long fiveN) {
  uint32_t pos = pf - rankBase;
  long long base = devOff[SCALE_IDX] + fiveN;
  uint32_t local = w - (uint32_t)RG;
  while (wd) {
    int bit = __ffs(wd) - 1;
    wd &= wd - 1u;
    uint32_t key = (local << 5) + (uint32_t)bit;
    int z = (int)(key & (uint32_t)MZ);
    int y = (int)((key >> LZ) & (uint32_t)MY);
    int x = (int)((key >> LYZ) & (uint32_t)MX);
    int bb = (int)(key >> LB);
    *(int4*)(out + base + 4LL * pos) = make_int4(bb, z, y, x);
    pos++;
  }
}

__global__ __launch_bounds__(256) void k_uniq(
    const uint2* __restrict__ pairs, const uint32_t* __restrict__ devRank,
    const long long* __restrict__ devOff, int* __restrict__ out, long long fiveN) {
  uint32_t w = blockIdx.x * 256 + threadIdx.x;  // < TOTALW, regions block-aligned
  uint2 pr = pairs[w];
  if (!pr.x) return;
  if (w < R_S4) {
    uniq_region<5, 13, 21, 31, 255, 255, R_S2, 0>(w, pr.x, pr.y, devRank[0], devOff, out, fiveN);
  } else if (w < R_S8) {
    uniq_region<4, 11, 18, 15, 127, 127, R_S4, 1>(w, pr.x, pr.y, devRank[1], devOff, out, fiveN);
  } else if (w < R_S1) {
    uniq_region<3, 9, 15, 7, 63, 63, R_S8, 2>(w, pr.x, pr.y, devRank[2], devOff, out, fiveN);
  } else {
    uniq_region<6, 15, 24, 63, 511, 511, R_S1, 3>(w, pr.x, pr.y, devRank[3], devOff, out, fiveN);
  }
}

extern "C" void kernel_launch(void* const* d_in, const int* in_sizes, int n_in,
                              void* d_out, int out_size, void* d_ws, size_t ws_size,
                              hipStream_t stream) {
  const float* pts = (const float*)d_in[0];
  const int* bidx = (const int*)d_in[1];
  int n = in_sizes[0] / 3;
  int* out = (int*)d_out;

  char* ws = (char*)d_ws;
  long long* devOff = (long long*)ws;                          // 5 * 8 B
  uint32_t* devRank = (uint32_t*)(ws + 64);                    // 4 * 4 B
  uint32_t* chunkSums = (uint32_t*)(ws + 256);                 // NB * 4 B
  uint32_t* bucketCount = (uint32_t*)(ws + 5120);              // 512 * 4 B
  uint32_t* bitmap = (uint32_t*)(ws + 8192);                   // TOTALW * 4 B
  uint2* pairs = (uint2*)(ws + 19243008);                      // TOTALW * 8 B
  uint32_t* keys = (uint32_t*)(ws + 57712640);                 // n * 4 B
  uint32_t* bucketData = (uint32_t*)(ws + 65712640);           // 512 * BCAP * 4 B

  const long long fourN = 4LL * n, fiveN = 5LL * n;
  const int gridN = (n + 255) / 256;

  hipMemsetAsync(bitmap, 0, (size_t)TOTALW * 4, stream);
  hipMemsetAsync(bucketCount, 0, NBUCKET * 4, stream);
  hipLaunchKernelGGL(k_key, dim3(256), dim3(256), 0, stream,
                     pts, bidx, n, keys, bitmap, bucketCount, bucketData);
  hipLaunchKernelGGL(k_bucket, dim3(NBUCKET), dim3(256), 0, stream,
                     bucketCount, bucketData, bitmap);
  hipLaunchKernelGGL(k_sumA, dim3(NB), dim3(256), 0, stream, bitmap, chunkSums);
  hipLaunchKernelGGL(k_scanB, dim3(1), dim3(256), 0, stream, chunkSums, devOff, devRank, fiveN);
  hipLaunchKernelGGL(k_pref, dim3(NB), dim3(256), 0, stream, bitmap, chunkSums, pairs);
  hipLaunchKernelGGL(k_write, dim3(gridN), dim3(256), 0, stream,
                     keys, n, pairs, devRank, devOff, out, fourN);
  hipLaunchKernelGGL(k_uniq, dim3(TOTALW / 256), dim3(256), 0, stream,
                     pairs, devRank, devOff, out, fiveN);
}